// Round 1
// baseline (179.359 us; speedup 1.0000x reference)
//
#include <hip/hip_runtime.h>
#include <hip/hip_bf16.h>

#define D_IN  4096
#define UNITS 4096
#define NNZ   262144
#define BATCH 1024
#define CAP   256   // bucket capacity per column (Poisson mean 64; P(>256) ~ 0)

// ---------------- CSC build ----------------

__global__ void zero_counts_kernel(int* counts) {
    int i = blockIdx.x * blockDim.x + threadIdx.x;
    if (i < UNITS) counts[i] = 0;
}

__global__ void scatter_kernel(const int* __restrict__ rows,
                               const int* __restrict__ cols,
                               const float* __restrict__ values,
                               int* __restrict__ counts,
                               int2* __restrict__ buckets) {
    int k = blockIdx.x * blockDim.x + threadIdx.x;
    if (k >= NNZ) return;
    int c = cols[k];
    int pos = atomicAdd(&counts[c], 1);
    if (pos < CAP) {
        int2 e;
        e.x = rows[k];
        e.y = __float_as_int(values[k]);
        buckets[c * CAP + pos] = e;
    }
}

// ---------------- transpose x [B, D] -> xT [D, B] ----------------

__global__ void transpose_x_kernel(const float* __restrict__ x,
                                   float* __restrict__ xT) {
    __shared__ float tile[32][33];
    const int nr = D_IN / 32;
    int r0 = (blockIdx.x % nr) * 32;   // column index of x == row of xT
    int b0 = (blockIdx.x / nr) * 32;
    int tx = threadIdx.x & 31, ty = threadIdx.x >> 5;   // 256 thr = 32x8
    #pragma unroll
    for (int i = 0; i < 32; i += 8)
        tile[ty + i][tx] = x[(size_t)(b0 + ty + i) * D_IN + r0 + tx];
    __syncthreads();
    #pragma unroll
    for (int i = 0; i < 32; i += 8)
        xT[(size_t)(r0 + ty + i) * BATCH + b0 + tx] = tile[tx][ty + i];
}

// ---------------- core SpMM: outT[c, b] = sum entries(c) xT[row, b]*val ----------------

__global__ __launch_bounds__(256) void spmm_kernel(const float* __restrict__ xT,
                                                   const int2* __restrict__ buckets,
                                                   const int* __restrict__ counts,
                                                   float* __restrict__ outT) {
    int c = blockIdx.x >> 2;                       // column
    int b = ((blockIdx.x & 3) << 8) + threadIdx.x; // batch element (4 tiles of 256)
    int n = counts[c];
    if (n > CAP) n = CAP;
    const int2* bk = buckets + (size_t)c * CAP;

    float a0 = 0.f, a1 = 0.f, a2 = 0.f, a3 = 0.f;
    int j = 0;
    for (; j + 4 <= n; j += 4) {
        int2 e0 = bk[j + 0];
        int2 e1 = bk[j + 1];
        int2 e2 = bk[j + 2];
        int2 e3 = bk[j + 3];
        a0 += xT[(size_t)e0.x * BATCH + b] * __int_as_float(e0.y);
        a1 += xT[(size_t)e1.x * BATCH + b] * __int_as_float(e1.y);
        a2 += xT[(size_t)e2.x * BATCH + b] * __int_as_float(e2.y);
        a3 += xT[(size_t)e3.x * BATCH + b] * __int_as_float(e3.y);
    }
    for (; j < n; ++j) {
        int2 e = bk[j];
        a0 += xT[(size_t)e.x * BATCH + b] * __int_as_float(e.y);
    }
    outT[(size_t)c * BATCH + b] = (a0 + a1) + (a2 + a3);
}

// ---------------- epilogue: out[b, c] = relu(outT[c, b] + bias[c]) ----------------

__global__ void epilogue_kernel(const float* __restrict__ outT,
                                const float* __restrict__ bias,
                                float* __restrict__ out) {
    __shared__ float tile[32][33];
    const int nc = UNITS / 32;
    int c0 = (blockIdx.x % nc) * 32;
    int b0 = (blockIdx.x / nc) * 32;
    int tx = threadIdx.x & 31, ty = threadIdx.x >> 5;   // 256 thr = 32x8
    #pragma unroll
    for (int i = 0; i < 32; i += 8)
        tile[ty + i][tx] = outT[(size_t)(c0 + ty + i) * BATCH + b0 + tx];
    __syncthreads();
    float bv = bias[c0 + tx];
    #pragma unroll
    for (int i = 0; i < 32; i += 8) {
        float v = tile[tx][ty + i] + bv;
        out[(size_t)(b0 + ty + i) * UNITS + c0 + tx] = v > 0.f ? v : 0.f;
    }
}

// ---------------- launch ----------------

extern "C" void kernel_launch(void* const* d_in, const int* in_sizes, int n_in,
                              void* d_out, int out_size, void* d_ws, size_t ws_size,
                              hipStream_t stream) {
    const float* x      = (const float*)d_in[0];
    const float* values = (const float*)d_in[1];
    const float* bias   = (const float*)d_in[2];
    const int*   rows   = (const int*)d_in[3];
    const int*   cols   = (const int*)d_in[4];
    float* out = (float*)d_out;

    // workspace layout
    char* ws = (char*)d_ws;
    float* xT      = (float*)(ws);                                  // 16 MB
    float* outT    = (float*)(ws + (size_t)16 * 1024 * 1024);       // 16 MB
    int2*  buckets = (int2*)(ws + (size_t)32 * 1024 * 1024);        //  8 MB
    int*   counts  = (int*)(ws + (size_t)40 * 1024 * 1024);         // 16 KB

    // 1. zero the per-column counters (ws is poisoned each launch)
    zero_counts_kernel<<<(UNITS + 255) / 256, 256, 0, stream>>>(counts);

    // 2. bucket-scatter COO -> per-column CSC
    scatter_kernel<<<(NNZ + 255) / 256, 256, 0, stream>>>(rows, cols, values,
                                                          counts, buckets);

    // 3. transpose x -> xT (coalesced batch-major rows)
    transpose_x_kernel<<<(D_IN / 32) * (BATCH / 32), 256, 0, stream>>>(x, xT);

    // 4. core sparse matmul into outT[c, b]
    spmm_kernel<<<UNITS * (BATCH / 256), 256, 0, stream>>>(xT, buckets, counts, outT);

    // 5. transpose + bias + relu -> out[b, c]
    epilogue_kernel<<<(UNITS / 32) * (BATCH / 32), 256, 0, stream>>>(outT, bias, out);
}

// Round 2
// 154.609 us; speedup vs baseline: 1.1601x; 1.1601x over previous
//
#include <hip/hip_runtime.h>
#include <hip/hip_bf16.h>

#define D_IN  4096
#define UNITS 4096
#define NNZ   262144
#define BATCH 1024
#define CAP   256   // bucket capacity per column (Poisson mean 64; P(>256) ~ 0)

// ---------------- CSC build: bucket scatter ----------------

__global__ void scatter_kernel(const int* __restrict__ rows,
                               const int* __restrict__ cols,
                               const float* __restrict__ values,
                               int* __restrict__ counts,
                               int2* __restrict__ buckets) {
    int k = blockIdx.x * blockDim.x + threadIdx.x;
    if (k >= NNZ) return;
    int c = cols[k];
    int pos = atomicAdd(&counts[c], 1);
    if (pos < CAP) {
        int2 e;
        e.x = rows[k];
        e.y = __float_as_int(values[k]);
        buckets[c * CAP + pos] = e;
    }
}

// ---------------- transpose x [B, D] -> xT bf16 [D, B] ----------------

__global__ void transpose_x_kernel(const float* __restrict__ x,
                                   unsigned short* __restrict__ xT) {
    __shared__ float tile[32][33];
    const int nr = D_IN / 32;
    int r0 = (blockIdx.x % nr) * 32;   // column of x == row of xT
    int b0 = (blockIdx.x / nr) * 32;
    int tx = threadIdx.x & 31, ty = threadIdx.x >> 5;   // 256 thr = 32x8
    #pragma unroll
    for (int i = 0; i < 32; i += 8)
        tile[ty + i][tx] = x[(size_t)(b0 + ty + i) * D_IN + r0 + tx];
    __syncthreads();
    #pragma unroll
    for (int i = 0; i < 32; i += 8) {
        unsigned bits = __float_as_uint(tile[tx][ty + i]);
        // round-to-nearest-even bf16 truncation
        unsigned r = (bits + 0x7FFFu + ((bits >> 16) & 1u)) >> 16;
        xT[(size_t)(r0 + ty + i) * BATCH + b0 + tx] = (unsigned short)r;
    }
}

// ---------------- core SpMM: outT[c, b] = sum entries(c) xT[row, b]*val ----------------

__global__ __launch_bounds__(256) void spmm_kernel(const unsigned short* __restrict__ xT,
                                                   const int2* __restrict__ buckets,
                                                   const int* __restrict__ counts,
                                                   float* __restrict__ outT) {
    __shared__ int   rowv[CAP];
    __shared__ float valv[CAP];
    const int c = blockIdx.x;
    int n = counts[c];
    if (n > CAP) n = CAP;
    if ((int)threadIdx.x < n) {
        int2 e = buckets[(size_t)c * CAP + threadIdx.x];
        rowv[threadIdx.x] = e.x;
        valv[threadIdx.x] = __int_as_float(e.y);
    }
    __syncthreads();

    const int b = threadIdx.x << 2;   // 4 consecutive batch elems per thread
    float a0 = 0.f, a1 = 0.f, a2 = 0.f, a3 = 0.f;

    int j = 0;
    for (; j + 4 <= n; j += 4) {
        ushort4 u0 = *(const ushort4*)(xT + (size_t)rowv[j + 0] * BATCH + b);
        ushort4 u1 = *(const ushort4*)(xT + (size_t)rowv[j + 1] * BATCH + b);
        ushort4 u2 = *(const ushort4*)(xT + (size_t)rowv[j + 2] * BATCH + b);
        ushort4 u3 = *(const ushort4*)(xT + (size_t)rowv[j + 3] * BATCH + b);
        float v0 = valv[j + 0], v1 = valv[j + 1];
        float v2 = valv[j + 2], v3 = valv[j + 3];
        a0 += __uint_as_float((unsigned)u0.x << 16) * v0;
        a1 += __uint_as_float((unsigned)u0.y << 16) * v0;
        a2 += __uint_as_float((unsigned)u0.z << 16) * v0;
        a3 += __uint_as_float((unsigned)u0.w << 16) * v0;
        a0 += __uint_as_float((unsigned)u1.x << 16) * v1;
        a1 += __uint_as_float((unsigned)u1.y << 16) * v1;
        a2 += __uint_as_float((unsigned)u1.z << 16) * v1;
        a3 += __uint_as_float((unsigned)u1.w << 16) * v1;
        a0 += __uint_as_float((unsigned)u2.x << 16) * v2;
        a1 += __uint_as_float((unsigned)u2.y << 16) * v2;
        a2 += __uint_as_float((unsigned)u2.z << 16) * v2;
        a3 += __uint_as_float((unsigned)u2.w << 16) * v2;
        a0 += __uint_as_float((unsigned)u3.x << 16) * v3;
        a1 += __uint_as_float((unsigned)u3.y << 16) * v3;
        a2 += __uint_as_float((unsigned)u3.z << 16) * v3;
        a3 += __uint_as_float((unsigned)u3.w << 16) * v3;
    }
    for (; j < n; ++j) {
        ushort4 u = *(const ushort4*)(xT + (size_t)rowv[j] * BATCH + b);
        float v = valv[j];
        a0 += __uint_as_float((unsigned)u.x << 16) * v;
        a1 += __uint_as_float((unsigned)u.y << 16) * v;
        a2 += __uint_as_float((unsigned)u.z << 16) * v;
        a3 += __uint_as_float((unsigned)u.w << 16) * v;
    }

    float4 r;
    r.x = a0; r.y = a1; r.z = a2; r.w = a3;
    *(float4*)(outT + (size_t)c * BATCH + b) = r;
}

// ---------------- epilogue: out[b, c] = relu(outT[c, b] + bias[c]) ----------------

__global__ void epilogue_kernel(const float* __restrict__ outT,
                                const float* __restrict__ bias,
                                float* __restrict__ out) {
    __shared__ float tile[32][33];
    const int nc = UNITS / 32;
    int c0 = (blockIdx.x % nc) * 32;
    int b0 = (blockIdx.x / nc) * 32;
    int tx = threadIdx.x & 31, ty = threadIdx.x >> 5;   // 256 thr = 32x8
    #pragma unroll
    for (int i = 0; i < 32; i += 8)
        tile[ty + i][tx] = outT[(size_t)(c0 + ty + i) * BATCH + b0 + tx];
    __syncthreads();
    float bv = bias[c0 + tx];
    #pragma unroll
    for (int i = 0; i < 32; i += 8) {
        float v = tile[tx][ty + i] + bv;
        out[(size_t)(b0 + ty + i) * UNITS + c0 + tx] = v > 0.f ? v : 0.f;
    }
}

// ---------------- launch ----------------

extern "C" void kernel_launch(void* const* d_in, const int* in_sizes, int n_in,
                              void* d_out, int out_size, void* d_ws, size_t ws_size,
                              hipStream_t stream) {
    const float* x      = (const float*)d_in[0];
    const float* values = (const float*)d_in[1];
    const float* bias   = (const float*)d_in[2];
    const int*   rows   = (const int*)d_in[3];
    const int*   cols   = (const int*)d_in[4];
    float* out = (float*)d_out;

    // workspace layout
    char* ws = (char*)d_ws;
    unsigned short* xT = (unsigned short*)(ws);                      //  8 MB
    float* outT    = (float*)(ws + (size_t)8 * 1024 * 1024);         // 16 MB
    int2*  buckets = (int2*)(ws + (size_t)24 * 1024 * 1024);         //  8 MB
    int*   counts  = (int*)(ws + (size_t)32 * 1024 * 1024);          // 16 KB

    // 1. zero per-column counters (ws re-poisoned each launch)
    hipMemsetAsync(counts, 0, UNITS * sizeof(int), stream);

    // 2. bucket-scatter COO -> per-column CSC
    scatter_kernel<<<(NNZ + 255) / 256, 256, 0, stream>>>(rows, cols, values,
                                                          counts, buckets);

    // 3. transpose + bf16-convert x -> xT
    transpose_x_kernel<<<(D_IN / 32) * (BATCH / 32), 256, 0, stream>>>(x, xT);

    // 4. core sparse matmul into outT[c, b]
    spmm_kernel<<<UNITS, 256, 0, stream>>>(xT, buckets, counts, outT);

    // 5. transpose + bias + relu -> out[b, c]
    epilogue_kernel<<<(UNITS / 32) * (BATCH / 32), 256, 0, stream>>>(outT, bias, out);
}

// Round 3
// 145.306 us; speedup vs baseline: 1.2344x; 1.0640x over previous
//
#include <hip/hip_runtime.h>
#include <hip/hip_bf16.h>

#define D_IN  4096
#define UNITS 4096
#define NNZ   262144
#define BATCH 1024
#define CAP   256    // bucket capacity per column (Poisson mean 64; round-1 pass proves max <= 256)
#define QB    256    // batch elems per quarter
#define NQ    4      // quarters

// ---------------- CSC build: bucket scatter ----------------

__global__ void scatter_kernel(const int* __restrict__ rows,
                               const int* __restrict__ cols,
                               const float* __restrict__ values,
                               int* __restrict__ counts,
                               int2* __restrict__ buckets) {
    int k = blockIdx.x * blockDim.x + threadIdx.x;
    if (k >= NNZ) return;
    int c = cols[k];
    int pos = atomicAdd(&counts[c], 1);
    if (pos < CAP) {
        int2 e;
        e.x = rows[k];
        e.y = __float_as_int(values[k]);
        buckets[c * CAP + pos] = e;
    }
}

// ---------------- transpose x [B, D] -> xT4 bf16 [NQ][D][QB] ----------------

__global__ void transpose_x_kernel(const float* __restrict__ x,
                                   unsigned short* __restrict__ xT4) {
    __shared__ float tile[32][33];
    const int nr = D_IN / 32;
    int r0 = (blockIdx.x % nr) * 32;   // column of x == row of xT
    int b0 = (blockIdx.x / nr) * 32;
    int tx = threadIdx.x & 31, ty = threadIdx.x >> 5;   // 256 thr = 32x8
    #pragma unroll
    for (int i = 0; i < 32; i += 8)
        tile[ty + i][tx] = x[(size_t)(b0 + ty + i) * D_IN + r0 + tx];
    __syncthreads();
    int q  = b0 >> 8;          // quarter (b0 multiple of 32, tx<32 -> uniform per block)
    int bq = (b0 & 255) + tx;  // offset within quarter
    #pragma unroll
    for (int i = 0; i < 32; i += 8) {
        unsigned bits = __float_as_uint(tile[tx][ty + i]);
        unsigned r = (bits + 0x7FFFu + ((bits >> 16) & 1u)) >> 16;  // RNE bf16
        xT4[((size_t)q * D_IN + (r0 + ty + i)) * QB + bq] = (unsigned short)r;
    }
}

// ---------------- core SpMM ----------------
// grid: NQ * 1024 blocks (quarter-major), 256 threads = 4 waves = 4 columns.
// Each wave: one (column, quarter); 64 lanes x 4 batch elems (8 B bf16 loads).
// Entry list is wave-uniform -> scalar s_load path, no LDS.

__global__ __launch_bounds__(256) void spmm_kernel(const unsigned short* __restrict__ xT4,
                                                   const int2* __restrict__ buckets,
                                                   const int* __restrict__ counts,
                                                   float* __restrict__ outT) {
    const int bx   = blockIdx.x;
    const int q    = bx >> 10;                 // quarter: phase-major dispatch
    const int cg   = bx & 1023;
    const int wave = __builtin_amdgcn_readfirstlane(threadIdx.x >> 6);
    const int lane = threadIdx.x & 63;
    const int c    = (cg << 2) | wave;         // wave-uniform column

    int n = counts[c];
    if (n > CAP) n = CAP;
    const int2* bk = buckets + (size_t)c * CAP;
    const unsigned short* bp = xT4 + (size_t)q * D_IN * QB + lane * 4;

    float a0 = 0.f, a1 = 0.f, a2 = 0.f, a3 = 0.f;
    int j = 0;
    for (; j + 4 <= n; j += 4) {
        int2 e0 = bk[j + 0];
        int2 e1 = bk[j + 1];
        int2 e2 = bk[j + 2];
        int2 e3 = bk[j + 3];
        uint2 u0 = *(const uint2*)(bp + (size_t)e0.x * QB);
        uint2 u1 = *(const uint2*)(bp + (size_t)e1.x * QB);
        uint2 u2 = *(const uint2*)(bp + (size_t)e2.x * QB);
        uint2 u3 = *(const uint2*)(bp + (size_t)e3.x * QB);
        float v0 = __int_as_float(e0.y), v1 = __int_as_float(e1.y);
        float v2 = __int_as_float(e2.y), v3 = __int_as_float(e3.y);
        a0 += __uint_as_float(u0.x << 16)          * v0;
        a1 += __uint_as_float(u0.x & 0xffff0000u)  * v0;
        a2 += __uint_as_float(u0.y << 16)          * v0;
        a3 += __uint_as_float(u0.y & 0xffff0000u)  * v0;
        a0 += __uint_as_float(u1.x << 16)          * v1;
        a1 += __uint_as_float(u1.x & 0xffff0000u)  * v1;
        a2 += __uint_as_float(u1.y << 16)          * v1;
        a3 += __uint_as_float(u1.y & 0xffff0000u)  * v1;
        a0 += __uint_as_float(u2.x << 16)          * v2;
        a1 += __uint_as_float(u2.x & 0xffff0000u)  * v2;
        a2 += __uint_as_float(u2.y << 16)          * v2;
        a3 += __uint_as_float(u2.y & 0xffff0000u)  * v2;
        a0 += __uint_as_float(u3.x << 16)          * v3;
        a1 += __uint_as_float(u3.x & 0xffff0000u)  * v3;
        a2 += __uint_as_float(u3.y << 16)          * v3;
        a3 += __uint_as_float(u3.y & 0xffff0000u)  * v3;
    }
    for (; j < n; ++j) {
        int2 e = bk[j];
        uint2 u = *(const uint2*)(bp + (size_t)e.x * QB);
        float v = __int_as_float(e.y);
        a0 += __uint_as_float(u.x << 16)          * v;
        a1 += __uint_as_float(u.x & 0xffff0000u)  * v;
        a2 += __uint_as_float(u.y << 16)          * v;
        a3 += __uint_as_float(u.y & 0xffff0000u)  * v;
    }

    float4 r; r.x = a0; r.y = a1; r.z = a2; r.w = a3;
    *(float4*)(outT + (size_t)c * BATCH + q * QB + lane * 4) = r;
}

// ---------------- epilogue: out[b, c] = relu(outT[c, b] + bias[c]) ----------------

__global__ void epilogue_kernel(const float* __restrict__ outT,
                                const float* __restrict__ bias,
                                float* __restrict__ out) {
    __shared__ float tile[32][33];
    const int nc = UNITS / 32;
    int c0 = (blockIdx.x % nc) * 32;
    int b0 = (blockIdx.x / nc) * 32;
    int tx = threadIdx.x & 31, ty = threadIdx.x >> 5;   // 256 thr = 32x8
    #pragma unroll
    for (int i = 0; i < 32; i += 8)
        tile[ty + i][tx] = outT[(size_t)(c0 + ty + i) * BATCH + b0 + tx];
    __syncthreads();
    float bv = bias[c0 + tx];
    #pragma unroll
    for (int i = 0; i < 32; i += 8) {
        float v = tile[tx][ty + i] + bv;
        out[(size_t)(b0 + ty + i) * UNITS + c0 + tx] = v > 0.f ? v : 0.f;
    }
}

// ---------------- launch ----------------

extern "C" void kernel_launch(void* const* d_in, const int* in_sizes, int n_in,
                              void* d_out, int out_size, void* d_ws, size_t ws_size,
                              hipStream_t stream) {
    const float* x      = (const float*)d_in[0];
    const float* values = (const float*)d_in[1];
    const float* bias   = (const float*)d_in[2];
    const int*   rows   = (const int*)d_in[3];
    const int*   cols   = (const int*)d_in[4];
    float* out = (float*)d_out;

    // workspace layout
    char* ws = (char*)d_ws;
    unsigned short* xT4 = (unsigned short*)(ws);                     //  8 MB
    float* outT    = (float*)(ws + (size_t)8 * 1024 * 1024);         // 16 MB
    int2*  buckets = (int2*)(ws + (size_t)24 * 1024 * 1024);         //  8 MB
    int*   counts  = (int*)(ws + (size_t)32 * 1024 * 1024);          // 16 KB

    // 1. zero per-column counters (ws re-poisoned each launch)
    hipMemsetAsync(counts, 0, UNITS * sizeof(int), stream);

    // 2. bucket-scatter COO -> per-column CSC
    scatter_kernel<<<(NNZ + 255) / 256, 256, 0, stream>>>(rows, cols, values,
                                                          counts, buckets);

    // 3. transpose + bf16-convert x -> xT4 [quarter][row][256]
    transpose_x_kernel<<<(D_IN / 32) * (BATCH / 32), 256, 0, stream>>>(x, xT4);

    // 4. core sparse matmul into outT[c, b] (quarter-major grid for L2 residency)
    spmm_kernel<<<NQ * 1024, 256, 0, stream>>>(xT4, buckets, counts, outT);

    // 5. transpose + bias + relu -> out[b, c]
    epilogue_kernel<<<(UNITS / 32) * (BATCH / 32), 256, 0, stream>>>(outT, bias, out);
}

// Round 4
// 135.143 us; speedup vs baseline: 1.3272x; 1.0752x over previous
//
#include <hip/hip_runtime.h>
#include <hip/hip_bf16.h>

#define D_IN  4096
#define UNITS 4096
#define NNZ   262144
#define BATCH 1024
#define CAP   256    // bucket capacity per column (Poisson mean 64; rounds 1-3 pass proves max <= 256)
#define QB    256    // batch elems per quarter
#define NQ    4      // quarters

#define SCAT_BLKS  (NNZ / 256)                    // 1024
#define TRANS_BLKS ((D_IN / 32) * (BATCH / 32))   // 4096

// ---------------- prep: scatter COO->CSC  +  transpose x -> xT4 bf16 [NQ][D][QB] ----------------

__global__ __launch_bounds__(256) void prep_kernel(const float* __restrict__ x,
                                                   const int* __restrict__ rows,
                                                   const int* __restrict__ cols,
                                                   const float* __restrict__ values,
                                                   int* __restrict__ counts,
                                                   int2* __restrict__ buckets,
                                                   unsigned short* __restrict__ xT4) {
    __shared__ float tile[32][33];
    int bx = blockIdx.x;
    if (bx < SCAT_BLKS) {
        // bucket scatter
        int k = bx * 256 + threadIdx.x;
        int c = cols[k];
        int pos = atomicAdd(&counts[c], 1);
        if (pos < CAP) {
            int2 e;
            e.x = rows[k];
            e.y = __float_as_int(values[k]);
            buckets[c * CAP + pos] = e;
        }
        return;
    }
    // transpose + bf16 convert
    bx -= SCAT_BLKS;
    const int nr = D_IN / 32;
    int r0 = (bx % nr) * 32;   // column of x == row of xT
    int b0 = (bx / nr) * 32;
    int tx = threadIdx.x & 31, ty = threadIdx.x >> 5;   // 256 thr = 32x8
    #pragma unroll
    for (int i = 0; i < 32; i += 8)
        tile[ty + i][tx] = x[(size_t)(b0 + ty + i) * D_IN + r0 + tx];
    __syncthreads();
    int q  = b0 >> 8;          // quarter (b0 multiple of 32 -> uniform per block)
    int bq = (b0 & 255) + tx;  // offset within quarter
    #pragma unroll
    for (int i = 0; i < 32; i += 8) {
        unsigned bits = __float_as_uint(tile[tx][ty + i]);
        unsigned r = (bits + 0x7FFFu + ((bits >> 16) & 1u)) >> 16;  // RNE bf16
        xT4[((size_t)q * D_IN + (r0 + ty + i)) * QB + bq] = (unsigned short)r;
    }
}

// ---------------- core SpMM ----------------
// grid: 4096 blocks, q = bx & 3 so each XCD (bx % 8) serves ONE 2 MB quarter -> L2-resident.
// wave = one (column, quarter). Half-wave split: lanes 0-31 process even entries,
// lanes 32-63 odd entries; each lane covers 8 batch elems via one 16 B bf16 load.
// Entry list is wave-uniform -> scalar s_load_dwordx4 (2 entries per fetch).

__device__ __forceinline__ void fma8(float* a, uint4 u, float v) {
    a[0] += __uint_as_float(u.x << 16)         * v;
    a[1] += __uint_as_float(u.x & 0xffff0000u) * v;
    a[2] += __uint_as_float(u.y << 16)         * v;
    a[3] += __uint_as_float(u.y & 0xffff0000u) * v;
    a[4] += __uint_as_float(u.z << 16)         * v;
    a[5] += __uint_as_float(u.z & 0xffff0000u) * v;
    a[6] += __uint_as_float(u.w << 16)         * v;
    a[7] += __uint_as_float(u.w & 0xffff0000u) * v;
}

__global__ __launch_bounds__(256) void spmm_kernel(const unsigned short* __restrict__ xT4,
                                                   const int2* __restrict__ buckets,
                                                   const int* __restrict__ counts,
                                                   float* __restrict__ outT) {
    const int bx   = blockIdx.x;
    const int q    = bx & 3;                   // (bx%8)&3 -> quarter pinned per XCD
    const int cg   = bx >> 2;
    const int wave = __builtin_amdgcn_readfirstlane(threadIdx.x >> 6);
    const int lane = threadIdx.x & 63;
    const bool hi  = lane >= 32;               // high half-wave handles odd entries
    const int c    = (cg << 2) | wave;         // wave-uniform column

    int n = counts[c];
    if (n > CAP) n = CAP;
    const int2* bk = buckets + (size_t)c * CAP;
    const unsigned short* bp = xT4 + (size_t)q * D_IN * QB + (lane & 31) * 8;

    float a[8];
    #pragma unroll
    for (int i = 0; i < 8; ++i) a[i] = 0.f;

    int j = 0;
    for (; j + 4 <= n; j += 4) {               // 2 pairs in flight
        uint4 e01 = *(const uint4*)(bk + j);
        uint4 e23 = *(const uint4*)(bk + j + 2);
        int   r0 = hi ? (int)e01.z : (int)e01.x;
        float v0 = hi ? __uint_as_float(e01.w) : __uint_as_float(e01.y);
        int   r1 = hi ? (int)e23.z : (int)e23.x;
        float v1 = hi ? __uint_as_float(e23.w) : __uint_as_float(e23.y);
        uint4 u0 = *(const uint4*)(bp + (size_t)r0 * QB);
        uint4 u1 = *(const uint4*)(bp + (size_t)r1 * QB);
        fma8(a, u0, v0);
        fma8(a, u1, v1);
    }
    for (; j + 2 <= n; j += 2) {               // single pair
        uint4 e01 = *(const uint4*)(bk + j);
        int   r0 = hi ? (int)e01.z : (int)e01.x;
        float v0 = hi ? __uint_as_float(e01.w) : __uint_as_float(e01.y);
        uint4 u0 = *(const uint4*)(bp + (size_t)r0 * QB);
        fma8(a, u0, v0);
    }
    if (j < n) {                               // odd tail: low half only
        int2 e = bk[j];
        float v = hi ? 0.f : __int_as_float(e.y);
        uint4 u = *(const uint4*)(bp + (size_t)e.x * QB);
        fma8(a, u, v);
    }

    // combine even/odd-entry partial sums across half-waves
    #pragma unroll
    for (int i = 0; i < 8; ++i) a[i] += __shfl_xor(a[i], 32, 64);

    if (lane < 32) {
        float* dst = outT + (size_t)c * BATCH + q * QB + (lane & 31) * 8;
        float4 r0; r0.x = a[0]; r0.y = a[1]; r0.z = a[2]; r0.w = a[3];
        float4 r1; r1.x = a[4]; r1.y = a[5]; r1.z = a[6]; r1.w = a[7];
        *(float4*)dst = r0;
        *(float4*)(dst + 4) = r1;
    }
}

// ---------------- epilogue: out[b, c] = relu(outT[c, b] + bias[c]) ----------------

__global__ void epilogue_kernel(const float* __restrict__ outT,
                                const float* __restrict__ bias,
                                float* __restrict__ out) {
    __shared__ float tile[32][33];
    const int nc = UNITS / 32;
    int c0 = (blockIdx.x % nc) * 32;
    int b0 = (blockIdx.x / nc) * 32;
    int tx = threadIdx.x & 31, ty = threadIdx.x >> 5;   // 256 thr = 32x8
    #pragma unroll
    for (int i = 0; i < 32; i += 8)
        tile[ty + i][tx] = outT[(size_t)(c0 + ty + i) * BATCH + b0 + tx];
    __syncthreads();
    float bv = bias[c0 + tx];
    #pragma unroll
    for (int i = 0; i < 32; i += 8) {
        float v = tile[tx][ty + i] + bv;
        out[(size_t)(b0 + ty + i) * UNITS + c0 + tx] = v > 0.f ? v : 0.f;
    }
}

// ---------------- launch ----------------

extern "C" void kernel_launch(void* const* d_in, const int* in_sizes, int n_in,
                              void* d_out, int out_size, void* d_ws, size_t ws_size,
                              hipStream_t stream) {
    const float* x      = (const float*)d_in[0];
    const float* values = (const float*)d_in[1];
    const float* bias   = (const float*)d_in[2];
    const int*   rows   = (const int*)d_in[3];
    const int*   cols   = (const int*)d_in[4];
    float* out = (float*)d_out;

    // workspace layout
    char* ws = (char*)d_ws;
    unsigned short* xT4 = (unsigned short*)(ws);                     //  8 MB
    float* outT    = (float*)(ws + (size_t)8 * 1024 * 1024);         // 16 MB
    int2*  buckets = (int2*)(ws + (size_t)24 * 1024 * 1024);         //  8 MB
    int*   counts  = (int*)(ws + (size_t)32 * 1024 * 1024);          // 16 KB

    // 1. zero per-column counters (ws re-poisoned each launch)
    hipMemsetAsync(counts, 0, UNITS * sizeof(int), stream);

    // 2. fused scatter + transpose/bf16-convert
    prep_kernel<<<SCAT_BLKS + TRANS_BLKS, 256, 0, stream>>>(x, rows, cols, values,
                                                            counts, buckets, xT4);

    // 3. core sparse matmul into outT[c, b] (quarter-per-XCD grid for L2 residency)
    spmm_kernel<<<NQ * 1024, 256, 0, stream>>>(xT4, buckets, counts, outT);

    // 4. transpose + bias + relu -> out[b, c]
    epilogue_kernel<<<(UNITS / 32) * (BATCH / 32), 256, 0, stream>>>(outT, bias, out);
}

// Round 5
// 132.336 us; speedup vs baseline: 1.3553x; 1.0212x over previous
//
#include <hip/hip_runtime.h>
#include <hip/hip_bf16.h>

#define D_IN  4096
#define UNITS 4096
#define NNZ   262144
#define BATCH 1024
#define CAP   256    // bucket capacity per column (Poisson mean 64; rounds 1-4 pass proves max <= 256)
#define QB    256    // batch elems per quarter
#define NQ    4      // quarters

#define SCAT_BLKS  (NNZ / 256)                    // 1024
#define TRANS_BLKS ((D_IN / 32) * (BATCH / 32))   // 4096

// ---------------- prep: scatter COO->CSC  +  transpose x -> xT4 bf16 [NQ][D][QB] ----------------

__global__ __launch_bounds__(256) void prep_kernel(const float* __restrict__ x,
                                                   const int* __restrict__ rows,
                                                   const int* __restrict__ cols,
                                                   const float* __restrict__ values,
                                                   int* __restrict__ counts,
                                                   int2* __restrict__ buckets,
                                                   unsigned short* __restrict__ xT4) {
    __shared__ float tile[32][33];
    int bx = blockIdx.x;
    if (bx < SCAT_BLKS) {
        // bucket scatter
        int k = bx * 256 + threadIdx.x;
        int c = cols[k];
        int pos = atomicAdd(&counts[c], 1);
        if (pos < CAP) {
            int2 e;
            e.x = rows[k];
            e.y = __float_as_int(values[k]);
            buckets[c * CAP + pos] = e;
        }
        return;
    }
    // transpose + bf16 convert
    bx -= SCAT_BLKS;
    const int nr = D_IN / 32;
    int r0 = (bx % nr) * 32;   // column of x == row of xT
    int b0 = (bx / nr) * 32;
    int tx = threadIdx.x & 31, ty = threadIdx.x >> 5;   // 256 thr = 32x8
    #pragma unroll
    for (int i = 0; i < 32; i += 8)
        tile[ty + i][tx] = x[(size_t)(b0 + ty + i) * D_IN + r0 + tx];
    __syncthreads();
    int q  = b0 >> 8;          // quarter (b0 multiple of 32 -> uniform per block)
    int bq = (b0 & 255) + tx;  // offset within quarter
    #pragma unroll
    for (int i = 0; i < 32; i += 8) {
        unsigned bits = __float_as_uint(tile[tx][ty + i]);
        unsigned r = (bits + 0x7FFFu + ((bits >> 16) & 1u)) >> 16;  // RNE bf16
        xT4[((size_t)q * D_IN + (r0 + ty + i)) * QB + bq] = (unsigned short)r;
    }
}

// ---------------- core SpMM ----------------
// grid: 4096 blocks, q = bx & 3 so each XCD (bx % 8) serves ONE 2 MB quarter -> L2-resident.
// wave = one (column, quarter). Half-wave split: lanes 0-31 process even entries,
// lanes 32-63 odd entries; each lane covers 8 batch elems via one 16 B bf16 load.
// Entry list is wave-uniform -> scalar fetches; 8-entry unroll keeps 4 scalar +
// 8 vector loads in flight to hide the s_load -> global_load dependent chain.

__device__ __forceinline__ void fma8(float* a, uint4 u, float v) {
    a[0] += __uint_as_float(u.x << 16)         * v;
    a[1] += __uint_as_float(u.x & 0xffff0000u) * v;
    a[2] += __uint_as_float(u.y << 16)         * v;
    a[3] += __uint_as_float(u.y & 0xffff0000u) * v;
    a[4] += __uint_as_float(u.z << 16)         * v;
    a[5] += __uint_as_float(u.z & 0xffff0000u) * v;
    a[6] += __uint_as_float(u.w << 16)         * v;
    a[7] += __uint_as_float(u.w & 0xffff0000u) * v;
}

__global__ __launch_bounds__(256) void spmm_kernel(const unsigned short* __restrict__ xT4,
                                                   const int2* __restrict__ buckets,
                                                   const int* __restrict__ counts,
                                                   float* __restrict__ outT) {
    const int bx   = blockIdx.x;
    const int q    = bx & 3;                   // (bx%8)&3 -> quarter pinned per XCD
    const int cg   = bx >> 2;
    const int wave = __builtin_amdgcn_readfirstlane(threadIdx.x >> 6);
    const int lane = threadIdx.x & 63;
    const bool hi  = lane >= 32;               // high half-wave handles odd entries
    const int c    = (cg << 2) | wave;         // wave-uniform column

    int n = counts[c];
    if (n > CAP) n = CAP;
    const int2* bk = buckets + (size_t)c * CAP;
    const char* bp = (const char*)(xT4 + (size_t)q * D_IN * QB + (lane & 31) * 8);

    float a[8];
    #pragma unroll
    for (int i = 0; i < 8; ++i) a[i] = 0.f;

    int j = 0;
    for (; j + 8 <= n; j += 8) {
        // 4 scalar entry fetches up front (compiler merges to wide s_load)
        uint4 e01 = *(const uint4*)(bk + j);
        uint4 e23 = *(const uint4*)(bk + j + 2);
        uint4 e45 = *(const uint4*)(bk + j + 4);
        uint4 e67 = *(const uint4*)(bk + j + 6);
        unsigned o0 = (hi ? e01.z : e01.x) * (QB * 2u);
        unsigned o1 = (hi ? e23.z : e23.x) * (QB * 2u);
        unsigned o2 = (hi ? e45.z : e45.x) * (QB * 2u);
        unsigned o3 = (hi ? e67.z : e67.x) * (QB * 2u);
        float v0 = __uint_as_float(hi ? e01.w : e01.y);
        float v1 = __uint_as_float(hi ? e23.w : e23.y);
        float v2 = __uint_as_float(hi ? e45.w : e45.y);
        float v3 = __uint_as_float(hi ? e67.w : e67.y);
        // 8 entries' worth of xT data: 4 vector loads in flight before any FMA
        uint4 u0 = *(const uint4*)(bp + o0);
        uint4 u1 = *(const uint4*)(bp + o1);
        uint4 u2 = *(const uint4*)(bp + o2);
        uint4 u3 = *(const uint4*)(bp + o3);
        fma8(a, u0, v0);
        fma8(a, u1, v1);
        fma8(a, u2, v2);
        fma8(a, u3, v3);
    }
    for (; j + 2 <= n; j += 2) {               // pair tail
        uint4 e01 = *(const uint4*)(bk + j);
        unsigned o0 = (hi ? e01.z : e01.x) * (QB * 2u);
        float v0 = __uint_as_float(hi ? e01.w : e01.y);
        uint4 u0 = *(const uint4*)(bp + o0);
        fma8(a, u0, v0);
    }
    if (j < n) {                               // odd tail: low half only
        int2 e = bk[j];
        float v = hi ? 0.f : __int_as_float(e.y);
        uint4 u = *(const uint4*)(bp + (unsigned)e.x * (QB * 2u));
        fma8(a, u, v);
    }

    // combine even/odd-entry partial sums across half-waves
    #pragma unroll
    for (int i = 0; i < 8; ++i) a[i] += __shfl_xor(a[i], 32, 64);

    if (lane < 32) {
        float* dst = outT + (size_t)c * BATCH + q * QB + (lane & 31) * 8;
        float4 r0; r0.x = a[0]; r0.y = a[1]; r0.z = a[2]; r0.w = a[3];
        float4 r1; r1.x = a[4]; r1.y = a[5]; r1.z = a[6]; r1.w = a[7];
        *(float4*)dst = r0;
        *(float4*)(dst + 4) = r1;
    }
}

// ---------------- epilogue: out[b, c] = relu(outT[c, b] + bias[c]) ----------------

__global__ void epilogue_kernel(const float* __restrict__ outT,
                                const float* __restrict__ bias,
                                float* __restrict__ out) {
    __shared__ float tile[32][33];
    const int nc = UNITS / 32;
    int c0 = (blockIdx.x % nc) * 32;
    int b0 = (blockIdx.x / nc) * 32;
    int tx = threadIdx.x & 31, ty = threadIdx.x >> 5;   // 256 thr = 32x8
    #pragma unroll
    for (int i = 0; i < 32; i += 8)
        tile[ty + i][tx] = outT[(size_t)(c0 + ty + i) * BATCH + b0 + tx];
    __syncthreads();
    float bv = bias[c0 + tx];
    #pragma unroll
    for (int i = 0; i < 32; i += 8) {
        float v = tile[tx][ty + i] + bv;
        out[(size_t)(b0 + ty + i) * UNITS + c0 + tx] = v > 0.f ? v : 0.f;
    }
}

// ---------------- launch ----------------

extern "C" void kernel_launch(void* const* d_in, const int* in_sizes, int n_in,
                              void* d_out, int out_size, void* d_ws, size_t ws_size,
                              hipStream_t stream) {
    const float* x      = (const float*)d_in[0];
    const float* values = (const float*)d_in[1];
    const float* bias   = (const float*)d_in[2];
    const int*   rows   = (const int*)d_in[3];
    const int*   cols   = (const int*)d_in[4];
    float* out = (float*)d_out;

    // workspace layout
    char* ws = (char*)d_ws;
    unsigned short* xT4 = (unsigned short*)(ws);                     //  8 MB
    float* outT    = (float*)(ws + (size_t)8 * 1024 * 1024);         // 16 MB
    int2*  buckets = (int2*)(ws + (size_t)24 * 1024 * 1024);         //  8 MB
    int*   counts  = (int*)(ws + (size_t)32 * 1024 * 1024);          // 16 KB

    // 1. zero per-column counters (ws re-poisoned each launch)
    hipMemsetAsync(counts, 0, UNITS * sizeof(int), stream);

    // 2. fused scatter + transpose/bf16-convert
    prep_kernel<<<SCAT_BLKS + TRANS_BLKS, 256, 0, stream>>>(x, rows, cols, values,
                                                            counts, buckets, xT4);

    // 3. core sparse matmul into outT[c, b] (quarter-per-XCD grid for L2 residency)
    spmm_kernel<<<NQ * 1024, 256, 0, stream>>>(xT4, buckets, counts, outT);

    // 4. transpose + bias + relu -> out[b, c]
    epilogue_kernel<<<(UNITS / 32) * (BATCH / 32), 256, 0, stream>>>(outT, bias, out);
}

// Round 6
// 126.110 us; speedup vs baseline: 1.4222x; 1.0494x over previous
//
#include <hip/hip_runtime.h>
#include <hip/hip_bf16.h>

#define D_IN  4096
#define UNITS 4096
#define NNZ   262144
#define BATCH 1024
#define CAP   256    // bucket capacity per column (Poisson mean 64; rounds 1-5 pass proves max <= 256)
#define QB    256    // batch elems per quarter
#define NQ    4      // quarters

#define SCAT_BLKS  (NNZ / 256)                    // 1024
#define TRANS_BLKS ((D_IN / 32) * (BATCH / 32))   // 4096

// ---------------- prep: scatter COO->CSC  +  transpose x -> xT4 bf16 [NQ][D][QB] ----------------

__global__ __launch_bounds__(256) void prep_kernel(const float* __restrict__ x,
                                                   const int* __restrict__ rows,
                                                   const int* __restrict__ cols,
                                                   const float* __restrict__ values,
                                                   int* __restrict__ counts,
                                                   int2* __restrict__ buckets,
                                                   unsigned short* __restrict__ xT4) {
    __shared__ float tile[32][33];
    int bx = blockIdx.x;
    if (bx < SCAT_BLKS) {
        // bucket scatter
        int k = bx * 256 + threadIdx.x;
        int c = cols[k];
        int pos = atomicAdd(&counts[c], 1);
        if (pos < CAP) {
            int2 e;
            e.x = rows[k];
            e.y = __float_as_int(values[k]);
            buckets[c * CAP + pos] = e;
        }
        return;
    }
    // transpose + bf16 convert
    bx -= SCAT_BLKS;
    const int nr = D_IN / 32;
    int r0 = (bx % nr) * 32;   // column of x == row of xT
    int b0 = (bx / nr) * 32;
    int tx = threadIdx.x & 31, ty = threadIdx.x >> 5;   // 256 thr = 32x8
    #pragma unroll
    for (int i = 0; i < 32; i += 8)
        tile[ty + i][tx] = x[(size_t)(b0 + ty + i) * D_IN + r0 + tx];
    __syncthreads();
    int q  = b0 >> 8;          // quarter (b0 multiple of 32 -> uniform per block)
    int bq = (b0 & 255) + tx;  // offset within quarter
    #pragma unroll
    for (int i = 0; i < 32; i += 8) {
        unsigned bits = __float_as_uint(tile[tx][ty + i]);
        unsigned r = (bits + 0x7FFFu + ((bits >> 16) & 1u)) >> 16;  // RNE bf16
        xT4[((size_t)q * D_IN + (r0 + ty + i)) * QB + bq] = (unsigned short)r;
    }
}

// ---------------- core SpMM + fused bias/relu/transpose epilogue ----------------
// grid: 4096 blocks, q = bx & 3 so each XCD (bx % 8) serves ONE 2 MB quarter -> L2-resident.
// wave = one (column, quarter); 4 waves of a block cover 4 CONSECUTIVE columns, so the
// block owns an out[256 b x 4 c] tile -> fused epilogue: bias+relu in-register, 4 KB LDS
// transpose, one float4 store per thread. No outT buffer, no epilogue kernel.

__device__ __forceinline__ void fma8(float* a, uint4 u, float v) {
    a[0] += __uint_as_float(u.x << 16)         * v;
    a[1] += __uint_as_float(u.x & 0xffff0000u) * v;
    a[2] += __uint_as_float(u.y << 16)         * v;
    a[3] += __uint_as_float(u.y & 0xffff0000u) * v;
    a[4] += __uint_as_float(u.z << 16)         * v;
    a[5] += __uint_as_float(u.z & 0xffff0000u) * v;
    a[6] += __uint_as_float(u.w << 16)         * v;
    a[7] += __uint_as_float(u.w & 0xffff0000u) * v;
}

__global__ __launch_bounds__(256) void spmm_kernel(const unsigned short* __restrict__ xT4,
                                                   const int2* __restrict__ buckets,
                                                   const int* __restrict__ counts,
                                                   const float* __restrict__ bias,
                                                   float* __restrict__ out) {
    __shared__ float tile[4][QB];              // [wave(col)][b_local]
    const int bx   = blockIdx.x;
    const int q    = bx & 3;                   // (bx%8)&3 -> quarter pinned per XCD
    const int cg   = bx >> 2;
    const int wave = __builtin_amdgcn_readfirstlane(threadIdx.x >> 6);
    const int lane = threadIdx.x & 63;
    const bool hi  = lane >= 32;               // high half-wave handles odd entries
    const int c    = (cg << 2) | wave;         // wave-uniform column

    int n = counts[c];
    if (n > CAP) n = CAP;
    const int2* bk = buckets + (size_t)c * CAP;
    const char* bp = (const char*)(xT4 + (size_t)q * D_IN * QB + (lane & 31) * 8);

    float a[8];
    #pragma unroll
    for (int i = 0; i < 8; ++i) a[i] = 0.f;

    int j = 0;
    for (; j + 8 <= n; j += 8) {
        // 4 scalar entry fetches up front (compiler merges to wide s_load)
        uint4 e01 = *(const uint4*)(bk + j);
        uint4 e23 = *(const uint4*)(bk + j + 2);
        uint4 e45 = *(const uint4*)(bk + j + 4);
        uint4 e67 = *(const uint4*)(bk + j + 6);
        unsigned o0 = (hi ? e01.z : e01.x) * (QB * 2u);
        unsigned o1 = (hi ? e23.z : e23.x) * (QB * 2u);
        unsigned o2 = (hi ? e45.z : e45.x) * (QB * 2u);
        unsigned o3 = (hi ? e67.z : e67.x) * (QB * 2u);
        float v0 = __uint_as_float(hi ? e01.w : e01.y);
        float v1 = __uint_as_float(hi ? e23.w : e23.y);
        float v2 = __uint_as_float(hi ? e45.w : e45.y);
        float v3 = __uint_as_float(hi ? e67.w : e67.y);
        // 8 entries' worth of xT data: 4 vector loads in flight before any FMA
        uint4 u0 = *(const uint4*)(bp + o0);
        uint4 u1 = *(const uint4*)(bp + o1);
        uint4 u2 = *(const uint4*)(bp + o2);
        uint4 u3 = *(const uint4*)(bp + o3);
        fma8(a, u0, v0);
        fma8(a, u1, v1);
        fma8(a, u2, v2);
        fma8(a, u3, v3);
    }
    for (; j + 2 <= n; j += 2) {               // pair tail
        uint4 e01 = *(const uint4*)(bk + j);
        unsigned o0 = (hi ? e01.z : e01.x) * (QB * 2u);
        float v0 = __uint_as_float(hi ? e01.w : e01.y);
        uint4 u0 = *(const uint4*)(bp + o0);
        fma8(a, u0, v0);
    }
    if (j < n) {                               // odd tail: low half only
        int2 e = bk[j];
        float v = hi ? 0.f : __int_as_float(e.y);
        uint4 u = *(const uint4*)(bp + (unsigned)e.x * (QB * 2u));
        fma8(a, u, v);
    }

    // combine even/odd-entry partial sums across half-waves
    #pragma unroll
    for (int i = 0; i < 8; ++i) a[i] += __shfl_xor(a[i], 32, 64);

    // fused epilogue: bias + relu, stage column-major in LDS
    float bv = bias[c];                        // wave-uniform -> s_load
    if (lane < 32) {
        float* dst = &tile[wave][(lane & 31) * 8];
        float4 r0, r1;
        r0.x = fmaxf(a[0] + bv, 0.f); r0.y = fmaxf(a[1] + bv, 0.f);
        r0.z = fmaxf(a[2] + bv, 0.f); r0.w = fmaxf(a[3] + bv, 0.f);
        r1.x = fmaxf(a[4] + bv, 0.f); r1.y = fmaxf(a[5] + bv, 0.f);
        r1.z = fmaxf(a[6] + bv, 0.f); r1.w = fmaxf(a[7] + bv, 0.f);
        *(float4*)dst = r0;
        *(float4*)(dst + 4) = r1;
    }
    __syncthreads();

    // each thread writes one float4 row-fragment of out[b, cg*4 .. cg*4+3]
    int t = threadIdx.x;
    float4 o;
    o.x = tile[0][t];
    o.y = tile[1][t];
    o.z = tile[2][t];
    o.w = tile[3][t];
    *(float4*)(out + (size_t)(q * QB + t) * UNITS + (cg << 2)) = o;
}

// ---------------- launch ----------------

extern "C" void kernel_launch(void* const* d_in, const int* in_sizes, int n_in,
                              void* d_out, int out_size, void* d_ws, size_t ws_size,
                              hipStream_t stream) {
    const float* x      = (const float*)d_in[0];
    const float* values = (const float*)d_in[1];
    const float* bias   = (const float*)d_in[2];
    const int*   rows   = (const int*)d_in[3];
    const int*   cols   = (const int*)d_in[4];
    float* out = (float*)d_out;

    // workspace layout
    char* ws = (char*)d_ws;
    unsigned short* xT4 = (unsigned short*)(ws);                     //  8 MB
    int2*  buckets = (int2*)(ws + (size_t)8 * 1024 * 1024);          //  8 MB
    int*   counts  = (int*)(ws + (size_t)16 * 1024 * 1024);          // 16 KB

    // 1. zero per-column counters (ws re-poisoned each launch)
    hipMemsetAsync(counts, 0, UNITS * sizeof(int), stream);

    // 2. fused scatter + transpose/bf16-convert
    prep_kernel<<<SCAT_BLKS + TRANS_BLKS, 256, 0, stream>>>(x, rows, cols, values,
                                                            counts, buckets, xT4);

    // 3. sparse matmul + fused bias/relu/transpose -> out[b, c]
    spmm_kernel<<<NQ * 1024, 256, 0, stream>>>(xT4, buckets, counts, bias, out);
}